// Round 4
// baseline (142.302 us; speedup 1.0000x reference)
//
#include <hip/hip_runtime.h>
#include <stdint.h>
#include <stddef.h>

#define IDIM 256

typedef __attribute__((ext_vector_type(8))) short bf16x8;
typedef __attribute__((ext_vector_type(4))) float f32x4;

__device__ __forceinline__ short f2bf(float f) {
    union { float f; unsigned u; } v; v.f = f;
    unsigned r = v.u + 0x7FFFu + ((v.u >> 16) & 1u);
    return (short)(r >> 16);
}

// LDS map: [0,73728) packed M tiles (72 x 1KB), [73728,74752) FI, [74752,78848) FW
#define FIOFF 73728
#define FWOFF 74752
#define LDSZ  78848

// Packed-tile base: active tiles (ti 16-rows, tj 32-cols), ti <= 2*tj+1.
// base = (tj^2+tj+ti)*1024. Tile rows are 64 B; swizzle stays within the row:
// SWZ(r) = XOR of byte-offset bits 4,5 only (2-way banking = free, m136).
#define SWZ(r) ((((r) >> 1) & 3) << 4)

__global__ __launch_bounds__(512, 4)
void fused_qform(const float* __restrict__ X, const float* __restrict__ K,
                 const float* __restrict__ FW, const int* __restrict__ FI,
                 float* __restrict__ out) {
    __shared__ char lds[LDSZ];
    const int tid  = threadIdx.x;
    const int lane = tid & 63;
    const int wave = tid >> 6;
    const int l15  = lane & 15;
    const int g    = lane >> 4;          // 0..3
    const int wrow = blockIdx.x * 128 + wave * 16;
    const int kbase = g * 8;

    // ---- stage FW (4KB, waves 0-3) + FI (1KB, wave 4) into LDS ----
    if (wave < 4) {
        const char* src = (const char*)FW + wave * 1024 + lane * 16;
        __builtin_amdgcn_global_load_lds(
            (const __attribute__((address_space(1))) unsigned*)src,
            (__attribute__((address_space(3))) unsigned*)(lds + FWOFF + wave * 1024),
            16, 0, 0);
    } else if (wave == 4) {
        const char* src = (const char*)FI + lane * 16;
        __builtin_amdgcn_global_load_lds(
            (const __attribute__((address_space(1))) unsigned*)src,
            (__attribute__((address_space(3))) unsigned*)(lds + FIOFF),
            16, 0, 0);
    }

    const float* xrow = X + (size_t)(wrow + l15) * IDIM + kbase;
    float4 pa[3], pb[3];               // ring-of-3 X prefetch (24 VGPR)

    // ================= build phase (fragA dies at scope end) =================
    {
        // K fragments (f32 -> bf16): lane holds K[16t + l15][kbase + e], k>=30 -> 0
        const int tb1 = wave;          // build columns 0..7
        const int tb2 = 15 - wave;     // build columns 8..15 (17 tiles/wave)
        bf16x8 fragA[16], fragB1, fragB2;
        #pragma unroll
        for (int t = 0; t < 16; ++t) {
            const float* kr = K + (16 * t + l15) * 30 + kbase;
            bf16x8 f;
            #pragma unroll
            for (int e = 0; e < 8; ++e) {
                float v = (kbase + e < 30) ? kr[e] : 0.f;
                f[e] = f2bf(v);
            }
            fragA[t] = f;
        }
        fragB1 = fragA[tb1];  // same index fn for A and B fragments
        fragB2 = fragA[tb2];
        const int fij1 = FI[16 * tb1 + l15];
        const int fij2 = FI[16 * tb2 + l15];

        // zero the 8 strictly-lower half-tiles (ti=2tj+1, low j-half)
        {
            const int ht = wave;
            const int r  = (lane >> 2) & 15;
            const int a  = lane & 3;
            const int zb = ((ht * (ht + 1) + (2 * ht + 1)) << 10) + r * 64 + ((a * 8) ^ SWZ(r));
            *(unsigned long long*)(lds + zb) = 0ull;
        }

        // barrier 1: FW/FI staged, K frags + fij loaded (vmcnt drain OK here)
        asm volatile("s_waitcnt vmcnt(0) lgkmcnt(0)" ::: "memory");
        __builtin_amdgcn_s_barrier();
        asm volatile("" ::: "memory");

        // issue X chunks 0..2 now; they stream during the build
        pa[0] = *(const float4*)(xrow + 0 * 32);
        pb[0] = *(const float4*)(xrow + 0 * 32 + 4);
        pa[1] = *(const float4*)(xrow + 1 * 32);
        pb[1] = *(const float4*)(xrow + 1 * 32 + 4);
        pa[2] = *(const float4*)(xrow + 2 * 32);
        pb[2] = *(const float4*)(xrow + 2 * 32 + 4);

        const f32x4 kz = (f32x4){0.f, 0.f, 0.f, 0.f};
        const int* ldsFI = (const int*)(lds + FIOFF);
        const float* ldsFW = (const float*)(lds + FWOFF);

        // Build tile (ta,tb): kk = fragA[ta] x fragB, D[row=g*4+q][col=l15].
        // M[i][j] = (j>i) ? kk*FW[FI[i]][FI[j]] : 0, bf16 into packed tile:
        // physical = base + i15*64 + (((tb&1)*32 + 2*l15) ^ SWZ(i15))
#define BUILD_TILE(ta, tb, fb, fij) do {                                          \
        f32x4 kk = __builtin_amdgcn_mfma_f32_16x16x32_bf16(fragA[ta], fb, kz, 0, 0, 0); \
        const int tjm = (tb) >> 1;                                                \
        const int mb  = ((tjm * (tjm + 1) + (ta)) << 10);                         \
        const int jb0 = (((tb) & 1) << 5) + 2 * l15;                              \
        const int j   = 16 * (tb) + l15;                                          \
        _Pragma("unroll")                                                         \
        for (int q = 0; q < 4; ++q) {                                             \
            const int i15 = g * 4 + q;                                            \
            const int i   = 16 * (ta) + i15;                                      \
            const float fw = ldsFW[ldsFI[16 * (ta) + i15] * 32 + (fij)];          \
            const float val = (j > i) ? kk[q] * fw : 0.f;                         \
            *(short*)(lds + mb + i15 * 64 + (jb0 ^ SWZ(i15))) = f2bf(val);        \
        }                                                                         \
    } while (0)

        #pragma unroll
        for (int ta = 0; ta < 16; ++ta) {
            if (ta <= tb1) BUILD_TILE(ta, tb1, fragB1, fij1);
        }
        #pragma unroll
        for (int ta = 0; ta < 16; ++ta) {
            if (ta <= tb2) BUILD_TILE(ta, tb2, fragB2, fij2);
        }
#undef BUILD_TILE
    }
    // ================= end build phase =================

    // barrier 2: M visible. NO vmcnt drain — X chunks stay in flight.
    asm volatile("s_waitcnt lgkmcnt(0)" ::: "memory");
    __builtin_amdgcn_s_barrier();
    asm volatile("" ::: "memory");

    // ---- main loop: tj-outer, ring-of-3 prefetch, acc[16] (64 VGPR) ----
    f32x4 acc[16];
    #pragma unroll
    for (int t = 0; t < 16; ++t) acc[t] = (f32x4){0.f, 0.f, 0.f, 0.f};

    const unsigned laneoff = (unsigned)l15 * 64u + (unsigned)((g * 16) ^ SWZ(l15));

    #pragma unroll
    for (int tj = 0; tj < 8; ++tj) {
        const int s = tj % 3;                      // compile-time after unroll
        const float4 fa = pa[s], fb = pb[s];
        bf16x8 af;
        af[0] = f2bf(fa.x); af[1] = f2bf(fa.y); af[2] = f2bf(fa.z); af[3] = f2bf(fa.w);
        af[4] = f2bf(fb.x); af[5] = f2bf(fb.y); af[6] = f2bf(fb.z); af[7] = f2bf(fb.w);
        if (tj < 5) {                              // re-issue this slot for chunk tj+3
            pa[s] = *(const float4*)(xrow + (tj + 3) * 32);
            pb[s] = *(const float4*)(xrow + (tj + 3) * 32 + 4);
        }
        #pragma unroll
        for (int ti = 0; ti < 16; ++ti) {
            if (ti <= 2 * tj + 1) {
                const bf16x8 b = *(const bf16x8*)(lds + ((tj * (tj + 1) + ti) << 10) + laneoff);
                acc[ti] = __builtin_amdgcn_mfma_f32_16x16x32_bf16(af, b, acc[ti], 0, 0, 0);
            }
        }
    }

    // ---- fold: out[m] = sum_n X[m][n] * Y[m][n]  (X re-read, L1/L2-hot) ----
    float psum[4] = {0.f, 0.f, 0.f, 0.f};
    const float* xm = X + (size_t)(wrow + g * 4) * IDIM + l15;
    #pragma unroll
    for (int ti = 0; ti < 16; ++ti) {
        #pragma unroll
        for (int q = 0; q < 4; ++q)
            psum[q] += xm[(size_t)q * IDIM + ti * 16] * acc[ti][q];
    }

    #pragma unroll
    for (int q = 0; q < 4; ++q) {
        float v = psum[q];
        v += __shfl_xor(v, 1, 64);
        v += __shfl_xor(v, 2, 64);
        v += __shfl_xor(v, 4, 64);
        v += __shfl_xor(v, 8, 64);
        psum[q] = v;
    }
    if (l15 == 0) {
        #pragma unroll
        for (int q = 0; q < 4; ++q)
            out[wrow + g * 4 + q] = psum[q];
    }
}

extern "C" void kernel_launch(void* const* d_in, const int* in_sizes, int n_in,
                              void* d_out, int out_size, void* d_ws, size_t ws_size,
                              hipStream_t stream) {
    const float* X  = (const float*)d_in[0];   // (65536, 256) f32
    const float* K  = (const float*)d_in[1];   // (256, 30)  f32
    const float* FW = (const float*)d_in[2];   // (32, 32)   f32
    const int*   FI = (const int*)d_in[3];     // (256,)     i32
    const int batch = in_sizes[0] / IDIM;      // 65536
    fused_qform<<<dim3(batch / 128), dim3(512), 0, stream>>>(X, K, FW, FI, (float*)d_out);
}

// Round 5
// 106.076 us; speedup vs baseline: 1.3415x; 1.3415x over previous
//
#include <hip/hip_runtime.h>
#include <stdint.h>
#include <stddef.h>

#define IDIM 256

typedef __attribute__((ext_vector_type(8))) short bf16x8;
typedef __attribute__((ext_vector_type(4))) float f32x4;

__device__ __forceinline__ short f2bf(float f) {
    union { float f; unsigned u; } v; v.f = f;
    unsigned r = v.u + 0x7FFFu + ((v.u >> 16) & 1u);
    return (short)(r >> 16);
}

// LDS map: [0,73728) packed M tiles (72 x 1KB), [73728,74752) FI,
//          [74752,78848) FW, [78848,95232) Kb fragment tiles (16 x 1KB).
#define FIOFF 73728
#define FWOFF 74752
#define KOFF  78848
#define LDSZ  95232

// Packed-tile base: active tiles (ti 16-rows, tj 32-cols), ti <= 2*tj+1.
// base = (tj^2+tj+ti)*1024. Tile rows are 64 B; swizzle stays within the row:
// SWZ(r) = XOR of byte-offset bits 4,5 only (2-way banking = free, m136).
#define SWZ(r) ((((r) >> 1) & 3) << 4)

__global__ __launch_bounds__(1024, 4)
void fused_qform(const float* __restrict__ X, const float* __restrict__ K,
                 const float* __restrict__ FW, const int* __restrict__ FI,
                 float* __restrict__ out) {
    __shared__ char lds[LDSZ];
    const int tid  = threadIdx.x;
    const int lane = tid & 63;
    const int wave = tid >> 6;           // 0..15
    const int l15  = lane & 15;
    const int g    = lane >> 4;          // 0..3
    const int wrow = blockIdx.x * 256 + wave * 16;
    const int kbase = g * 8;

    // ---- stage FW (4KB, waves 0-3) + FI (1KB, wave 4) into LDS ----
    if (wave < 4) {
        const char* src = (const char*)FW + wave * 1024 + lane * 16;
        __builtin_amdgcn_global_load_lds(
            (const __attribute__((address_space(1))) unsigned*)src,
            (__attribute__((address_space(3))) unsigned*)(lds + FWOFF + wave * 1024),
            16, 0, 0);
    } else if (wave == 4) {
        const char* src = (const char*)FI + lane * 16;
        __builtin_amdgcn_global_load_lds(
            (const __attribute__((address_space(1))) unsigned*)src,
            (__attribute__((address_space(3))) unsigned*)(lds + FIOFF),
            16, 0, 0);
    }

    // ---- stage Kb fragment tiles: wave w writes tile t=w ----
    // Kb tile t, lane l holds K[16t + l15][g*8+e] (e=0..7, k>=30 -> 0) as bf16
    // at lds[KOFF + t*1024 + l*16] — exactly the 16x16x32 A/B fragment bytes.
    {
        const float* kr = K + (size_t)(16 * wave + l15) * 30 + kbase;
        bf16x8 f;
        #pragma unroll
        for (int e = 0; e < 8; ++e) {
            float v = (kbase + e < 30) ? kr[e] : 0.f;
            f[e] = f2bf(v);
        }
        *(bf16x8*)(lds + KOFF + wave * 1024 + lane * 16) = f;
    }

    // ---- zero the 8 strictly-lower half-tiles (ti=2tj+1, low j-half) ----
    // 8 halftiles x 16 rows x 32 logical bytes = 4KB; 1024 threads x 4B.
    {
        const int ht = tid >> 7;               // 0..7
        const int r  = (tid >> 3) & 15;        // row
        const int a  = tid & 7;                // 4B slot in low half
        const int zb = ((ht * (ht + 1) + (2 * ht + 1)) << 10) + r * 64 + ((a * 4) ^ SWZ(r));
        *(unsigned*)(lds + zb) = 0u;
    }

    // ---- barrier 1: FW/FI/Kb staged + zeros written (full drain OK here) ----
    asm volatile("s_waitcnt vmcnt(0) lgkmcnt(0)" ::: "memory");
    __builtin_amdgcn_s_barrier();
    asm volatile("" ::: "memory");

    // ---- issue X chunks 0..2; they stream during the build ----
    const float* xrow = X + (size_t)(wrow + l15) * IDIM + kbase;
    float4 pa[3], pb[3];               // ring-of-3 X prefetch (24 VGPR)
    pa[0] = *(const float4*)(xrow + 0 * 32);
    pb[0] = *(const float4*)(xrow + 0 * 32 + 4);
    pa[1] = *(const float4*)(xrow + 1 * 32);
    pb[1] = *(const float4*)(xrow + 1 * 32 + 4);
    pa[2] = *(const float4*)(xrow + 2 * 32);
    pb[2] = *(const float4*)(xrow + 2 * 32 + 4);

    // ================= build phase (zero VMEM; frags via ds_read) ===========
    {
        const f32x4 kz = (f32x4){0.f, 0.f, 0.f, 0.f};
        const int* ldsFI = (const int*)(lds + FIOFF);
        const float* ldsFW = (const float*)(lds + FWOFF);

        const int v   = wave >> 1;     // column pair (v, 15-v)
        const int par = wave & 1;      // even/odd ta split within the pair
        const int tb1 = v;
        const int tb2 = 15 - v;
        const bf16x8 bf1 = *(const bf16x8*)(lds + KOFF + tb1 * 1024 + lane * 16);
        const bf16x8 bf2 = *(const bf16x8*)(lds + KOFF + tb2 * 1024 + lane * 16);
        const int fij1 = ldsFI[16 * tb1 + l15];
        const int fij2 = ldsFI[16 * tb2 + l15];

        // Build tile (ta,tb): kk = Afrag(ta) x Bfrag(tb), D[row=g*4+q][col=l15].
        // M[i][j] = (j>i) ? kk*FW[FI[i]][FI[j]] : 0, bf16 into packed tile:
        // physical = base + i15*64 + (((tb&1)*32 + 2*l15) ^ SWZ(i15))
#define BUILD_TILE(ta, tb, fb, fij) do {                                          \
        const bf16x8 aa = *(const bf16x8*)(lds + KOFF + (ta) * 1024 + lane * 16); \
        f32x4 kk = __builtin_amdgcn_mfma_f32_16x16x32_bf16(aa, fb, kz, 0, 0, 0);  \
        const int tjm = (tb) >> 1;                                                \
        const int mb  = ((tjm * (tjm + 1) + (ta)) << 10);                         \
        const int jb0 = (((tb) & 1) << 5) + 2 * l15;                              \
        const int j   = 16 * (tb) + l15;                                          \
        _Pragma("unroll")                                                         \
        for (int q = 0; q < 4; ++q) {                                             \
            const int i15 = g * 4 + q;                                            \
            const int i   = 16 * (ta) + i15;                                      \
            const float fw = ldsFW[ldsFI[16 * (ta) + i15] * 32 + (fij)];          \
            const float val = (j > i) ? kk[q] * fw : 0.f;                         \
            *(short*)(lds + mb + i15 * 64 + (jb0 ^ SWZ(i15))) = f2bf(val);        \
        }                                                                         \
    } while (0)

        #pragma unroll
        for (int ta = 0; ta < 16; ++ta) {
            if ((ta & 1) == par) {
                if (ta <= tb1) BUILD_TILE(ta, tb1, bf1, fij1);
                if (ta <= tb2) BUILD_TILE(ta, tb2, bf2, fij2);
            }
        }
#undef BUILD_TILE
    }
    // ================= end build phase =================

    // barrier 2: M visible. NO vmcnt drain — X chunks stay in flight.
    asm volatile("s_waitcnt lgkmcnt(0)" ::: "memory");
    __builtin_amdgcn_s_barrier();
    asm volatile("" ::: "memory");

    // ---- main loop: tj-outer, ring-of-3 prefetch, acc[16] ----
    f32x4 acc[16];
    #pragma unroll
    for (int t = 0; t < 16; ++t) acc[t] = (f32x4){0.f, 0.f, 0.f, 0.f};

    const unsigned laneoff = (unsigned)l15 * 64u + (unsigned)((g * 16) ^ SWZ(l15));

    #pragma unroll
    for (int tj = 0; tj < 8; ++tj) {
        const int s = tj % 3;                      // compile-time after unroll
        const float4 fa = pa[s], fb = pb[s];
        bf16x8 af;
        af[0] = f2bf(fa.x); af[1] = f2bf(fa.y); af[2] = f2bf(fa.z); af[3] = f2bf(fa.w);
        af[4] = f2bf(fb.x); af[5] = f2bf(fb.y); af[6] = f2bf(fb.z); af[7] = f2bf(fb.w);
        if (tj < 5) {                              // re-issue this slot for chunk tj+3
            pa[s] = *(const float4*)(xrow + (tj + 3) * 32);
            pb[s] = *(const float4*)(xrow + (tj + 3) * 32 + 4);
        }
        #pragma unroll
        for (int ti = 0; ti < 16; ++ti) {
            if (ti <= 2 * tj + 1) {
                const bf16x8 b = *(const bf16x8*)(lds + ((tj * (tj + 1) + ti) << 10) + laneoff);
                acc[ti] = __builtin_amdgcn_mfma_f32_16x16x32_bf16(af, b, acc[ti], 0, 0, 0);
            }
        }
    }

    // ---- fold: out[m] = sum_n X[m][n] * Y[m][n]  (X re-read, L2/L3-hot) ----
    float psum[4] = {0.f, 0.f, 0.f, 0.f};
    const float* xm = X + (size_t)(wrow + g * 4) * IDIM + l15;
    #pragma unroll
    for (int ti = 0; ti < 16; ++ti) {
        #pragma unroll
        for (int q = 0; q < 4; ++q)
            psum[q] += xm[(size_t)q * IDIM + ti * 16] * acc[ti][q];
    }

    #pragma unroll
    for (int q = 0; q < 4; ++q) {
        float v = psum[q];
        v += __shfl_xor(v, 1, 64);
        v += __shfl_xor(v, 2, 64);
        v += __shfl_xor(v, 4, 64);
        v += __shfl_xor(v, 8, 64);
        psum[q] = v;
    }
    if (l15 == 0) {
        #pragma unroll
        for (int q = 0; q < 4; ++q)
            out[wrow + g * 4 + q] = psum[q];
    }
}

extern "C" void kernel_launch(void* const* d_in, const int* in_sizes, int n_in,
                              void* d_out, int out_size, void* d_ws, size_t ws_size,
                              hipStream_t stream) {
    const float* X  = (const float*)d_in[0];   // (65536, 256) f32
    const float* K  = (const float*)d_in[1];   // (256, 30)  f32
    const float* FW = (const float*)d_in[2];   // (32, 32)   f32
    const int*   FI = (const int*)d_in[3];     // (256,)     i32
    const int batch = in_sizes[0] / IDIM;      // 65536
    fused_qform<<<dim3(batch / 256), dim3(1024), 0, stream>>>(X, K, FW, FI, (float*)d_out);
}